// Round 7
// baseline (273.501 us; speedup 1.0000x reference)
//
#include <hip/hip_runtime.h>
#include <stdint.h>

typedef unsigned short u16;
typedef unsigned int   u32;
typedef __attribute__((ext_vector_type(4)))  float f32x4;
typedef __attribute__((ext_vector_type(16))) float f32x16;
typedef __attribute__((ext_vector_type(8)))  short short8;
typedef __attribute__((ext_vector_type(8)))  u16   u16x8;
typedef __attribute__((ext_vector_type(4)))  u16   u16x4;
typedef __attribute__((ext_vector_type(4)))  u32   u32x4;
typedef __attribute__((ext_vector_type(4)))  float fv4;

#define T_LEN 1024
#define EMB   1024
#define SPAD  1088   // padded src len (17*64), valid 0..1024
#define LOG2E 1.44269504f

// workspace layout (bytes) — packed with lifetime sharing
#define OFF_QX   (0ull)
#define OFF_VT   (0ull)          // vt shares qx region (qx dead after qkv)
#define OFF_WT   (8912896ull)
#define OFF_QB   (17301504ull)
#define OFF_KB   (25690112ull)
#define OFF_VB   (34603008ull)
#define OFF_AT   (34603008ull)   // at shares vb region (vb dead after k_mid)
#define OFF_GATE (43515904ull)
#define OFF_PB   (43778048ull)
#define OFF_AUX  (43909120ull)

__device__ __forceinline__ u16 f2bf(float f) {
  uint32_t u = __builtin_bit_cast(uint32_t, f);
  u += 0x7FFFu + ((u >> 16) & 1u);
  return (u16)(u >> 16);
}
__device__ __forceinline__ float bf2f(u16 s) {
  uint32_t u = ((uint32_t)s) << 16;
  return __builtin_bit_cast(float, u);
}
__device__ __forceinline__ void gld_lds16(const void* gp, void* lp) {
  __builtin_amdgcn_global_load_lds(
      (const __attribute__((address_space(1))) uint32_t*)(uintptr_t)(gp),
      (__attribute__((address_space(3))) uint32_t*)(uintptr_t)(lp),
      16, 0, 0);
}

// ================= k_prep: convert_q + transw + pb/aux (blockIdx-ranged) ====
__global__ void k_prep(const float* __restrict__ q, u16* __restrict__ qx,
                       const float* __restrict__ w0, const float* __restrict__ w1,
                       const float* __restrict__ w2, const float* __restrict__ w3,
                       u16* __restrict__ wt,
                       const float* __restrict__ rel_emb, float* __restrict__ pbtab,
                       const float* __restrict__ grep_w, const float* __restrict__ grep_b,
                       float* __restrict__ aux) {
  __shared__ float tile[32][33];
  const int bid = blockIdx.x, tid = threadIdx.x;
  if (bid < 4096) {
    // query f32 -> bf16
    int i = bid * 256 + tid;
    fv4 v = *((const fv4*)q + i);
    u16x4 o = { f2bf(v[0]), f2bf(v[1]), f2bf(v[2]), f2bf(v[3]) };
    *((u16x4*)qx + i) = o;
  } else if (bid < 8192) {
    // weight transpose + convert: wt[z][n][k] = w_z[k][n]
    int b2 = bid - 4096;
    int z = b2 >> 10, xy = b2 & 1023;
    int r0 = (xy >> 5) * 32, c0 = (xy & 31) * 32;
    const float* w = (z == 0) ? w0 : (z == 1) ? w1 : (z == 2) ? w2 : w3;
    int tx = tid & 31, ty = tid >> 5;
    #pragma unroll
    for (int j = 0; j < 32; j += 8)
      tile[ty + j][tx] = w[(size_t)(r0 + ty + j) * EMB + c0 + tx];
    __syncthreads();
    u16* o = wt + (size_t)z * EMB * EMB;
    #pragma unroll
    for (int j = 0; j < 32; j += 8)
      o[(size_t)(c0 + ty + j) * EMB + r0 + tx] = f2bf(tile[tx][ty + j]);
  } else {
    // REVERSED pb table (pre-scaled by log2e): pbtab[h][i] = pb(rel=1024-i)*log2e
    int i = (bid - 8192) * 256 + tid;    // 0..2047
    int rel = 1024 - i;
    int bucket = (rel > 0) ? 16 : 0;
    int r = rel < 0 ? -rel : rel;
    int bidx;
    if (r < 8) bidx = r;
    else {
      float lf = __logf((float)r / 8.0f + 1e-6f) * (1.0f / logf(16.0f)) * 8.0f;
      int large = 8 + (int)lf;
      bidx = large < 15 ? large : 15;
    }
    bucket += bidx;
    #pragma unroll
    for (int hh = 0; hh < 16; ++hh) pbtab[hh * 2048 + i] = rel_emb[bucket * 16 + hh] * LOG2E;
    if (bid == 8192) {
      if (tid < 64) {
        float s = 0.f;
        #pragma unroll
        for (int j = 0; j < 8; ++j) s += grep_w[tid * 8 + j];
        aux[tid] = s;
      } else if (tid == 64) {
        float s = 0.f;
        #pragma unroll
        for (int j = 0; j < 8; ++j) s += grep_b[j];
        aux[64] = s;
      }
    }
  }
}

// ---------------- m97-style 128x128 bf16 GEMM core (B^T input) --------------
__device__ __forceinline__ void gemm_tile(const u16* __restrict__ A, const u16* __restrict__ Bt,
                                          int m0, int n0, u16* As, u16* Bs, f32x4 acc[4][4]) {
  const int tid = threadIdx.x;
  const int lane = tid & 63, wid = tid >> 6;
  const int wm = wid >> 1, wn = wid & 1;
  const int l15 = lane & 15, l4 = lane >> 4;
  for (int kt = 0; kt < EMB; kt += 32) {
    #pragma unroll
    for (int i = 0; i < 2; ++i) {
      int cw = wid * 64 + i * 256;   // wave-uniform chunk base
      int c = cw + lane;
      int row = c >> 2, cb = c & 3;
      gld_lds16(A  + (size_t)(m0 + row) * EMB + kt + cb * 8, (char*)As + (size_t)cw * 16);
      gld_lds16(Bt + (size_t)(n0 + row) * EMB + kt + cb * 8, (char*)Bs + (size_t)cw * 16);
    }
    __syncthreads();
    short8 a[4], b[4];
    #pragma unroll
    for (int f = 0; f < 4; ++f) {
      a[f] = *(const short8*)(As + (wm * 64 + f * 16 + l15) * 32 + l4 * 8);
      b[f] = *(const short8*)(Bs + (wn * 64 + f * 16 + l15) * 32 + l4 * 8);
    }
    #pragma unroll
    for (int mi = 0; mi < 4; ++mi)
      #pragma unroll
      for (int ni = 0; ni < 4; ++ni)
        acc[mi][ni] = __builtin_amdgcn_mfma_f32_16x16x32_bf16(a[mi], b[ni], acc[mi][ni], 0, 0, 0);
    __syncthreads();
  }
}

// ---------------- fused QKV projection GEMM (N = 3072), scrambled scatter ---
__global__ __launch_bounds__(256, 2) void k_qkv_gemm(const u16* __restrict__ qx, const u16* __restrict__ wt,
    const float* __restrict__ qbias, const float* __restrict__ kbias, const float* __restrict__ vbias,
    u16* __restrict__ qb, u16* __restrict__ kb, u16* __restrict__ vb) {
  __shared__ u16 lds[8192];
  f32x4 acc[4][4];
  #pragma unroll
  for (int i = 0; i < 4; ++i)
    #pragma unroll
    for (int j = 0; j < 4; ++j) acc[i][j] = (f32x4){0.f, 0.f, 0.f, 0.f};
  const int m0 = blockIdx.y * 128, n0g = blockIdx.x * 128;   // n0g in [0,3072)
  gemm_tile(qx, wt, m0, n0g, lds, lds + 4096, acc);          // wt is [3072][1024]
  const int z = n0g >> 10;
  const float* bias = (z == 0) ? qbias : (z == 1) ? kbias : vbias;
  const int lane = threadIdx.x & 63, wid = threadIdx.x >> 6;
  const int wm = wid >> 1, wn = wid & 1, l15 = lane & 15, l4 = lane >> 4;
  #pragma unroll
  for (int ni = 0; ni < 4; ++ni) {
    int colg = n0g + wn * 64 + ni * 16 + l15;
    int col = colg & 1023;
    float bv = bias[col];
    int h = col >> 6, d = col & 63;
    #pragma unroll
    for (int mi = 0; mi < 4; ++mi) {
      #pragma unroll
      for (int r = 0; r < 4; ++r) {
        int row = m0 + wm * 64 + mi * 16 + l4 * 4 + r;
        int t = row >> 2, b = row & 3;     // input rows are (t,b) interleaved
        float v = acc[mi][ni][r] + bv;
        if (z == 0) {
          int x = b * 16 + (t >> 6), u = ((t & 63) << 4) + h;
          qb[((size_t)x * 1024 + u) * 64 + d] = f2bf(v * (LOG2E / 256.0f));
        } else {
          int w = t * 16 + h;
          int j = w / 1025;
          int u = w - j * 1025;
          int x = b * 16 + j;
          if (z == 1) kb[((size_t)x * SPAD + u) * 64 + d] = f2bf(v);
          else        vb[((size_t)x * SPAD + u) * 64 + d] = f2bf(v);
        }
      }
    }
  }
}

// ================= k_mid: vtrans + bias_kv injection + gate =================
__global__ void k_mid(const u16* __restrict__ vb, u16* __restrict__ vt, u16* __restrict__ kb,
                      const float* __restrict__ bias_k, const float* __restrict__ bias_v,
                      const u16* __restrict__ qb, const float* __restrict__ aux,
                      const float* __restrict__ grep_a, float* __restrict__ gate) {
  __shared__ u16 t[64][72];
  const int bid = blockIdx.x, tid = threadIdx.x;
  if (bid < 1088) {
    // V transpose vb[x][u][d] -> vt[x][d][u], with bias_v row injection
    const int x = bid / 17, uc = bid - (bid / 17) * 17;
    const int u0 = uc * 64;
    const int ur = tid >> 2, c0 = (tid & 3) * 16;
    const u16* src = vb + ((size_t)x * SPAD + u0 + ur) * 64 + c0;
    u16x8 a0 = *(const u16x8*)(src);
    u16x8 a1 = *(const u16x8*)(src + 8);
    const int ug = u0 + ur;
    if ((x & 15) == 15 && ug >= 1009 && ug <= 1024) {
      const float* bs = bias_v + (ug - 1009) * 64 + c0;   // bias_v[h][d], h = ug-1009
      #pragma unroll
      for (int i = 0; i < 8; ++i) { a0[i] = f2bf(bs[i]); a1[i] = f2bf(bs[8 + i]); }
    }
    *(u16x8*)(&t[ur][c0]) = a0;
    *(u16x8*)(&t[ur][c0 + 8]) = a1;
    __syncthreads();
    const int d = tid >> 2, j = tid & 3;
    u16x8 o0, o1;
    #pragma unroll
    for (int i = 0; i < 8; ++i) o0[i] = t[j * 16 + i][d];
    #pragma unroll
    for (int i = 0; i < 8; ++i) o1[i] = t[j * 16 + 8 + i][d];
    u16* dst = vt + ((size_t)x * 64 + d) * SPAD + u0 + j * 16;
    *(u16x8*)(dst) = o0;
    *(u16x8*)(dst + 8) = o1;
    // bias_k rows (x%16==15, u=1009..1024) written by the uc==16 blocks
    if ((x & 15) == 15 && uc == 16) {
      int k = tid * 4;                 // 0..1023, 16 rows x 64 d
      int hh = k >> 6, dd = k & 63;
      u16x4 kv;
      #pragma unroll
      for (int e = 0; e < 4; ++e) kv[e] = f2bf(bias_k[hh * 64 + dd + e]);
      *(u16x4*)(kb + ((size_t)x * SPAD + 1009 + hh) * 64 + dd) = kv;
    }
  } else {
    // gate[x][u] = sigmoid(q_row . wsum + bg) * grep_a[x&15]
    int gb = bid - 1088;
    int lane = tid & 63, wid = tid >> 6;
    int row0 = (gb * 4 + wid) * 8;
    int sub = lane >> 3, d0 = (lane & 7) * 8;
    int item = row0 + sub;
    u16x8 q8 = *(const u16x8*)(qb + (size_t)item * 64 + d0);
    float acc = 0.f;
    #pragma unroll
    for (int j = 0; j < 8; ++j) acc += bf2f(q8[j]) * aux[d0 + j];
    acc += __shfl_xor(acc, 1);
    acc += __shfl_xor(acc, 2);
    acc += __shfl_xor(acc, 4);
    if ((lane & 7) == 0) {
      float v = acc * (256.0f / LOG2E) + aux[64];
      float s = 1.0f / (1.0f + __expf(-v));
      gate[item] = s * grep_a[(item >> 10) & 15];
    }
  }
}

// ---------------- fused flash attention v6 ----------------------------------
// Swapped-operand 32x32 MFMA, zero LDS in loop. 2-way s-split (fixed-max
// partials add directly), 4 waves/block = 2 row-groups x 2 s-halves,
// grid 1024 -> 4 waves/SIMD. Far-bucket pb: |rel|>=128 chunks skip LDS reads.
__global__ __launch_bounds__(256, 4) void k_attn(const u16* __restrict__ qb, const u16* __restrict__ kb,
    const u16* __restrict__ vt, const float* __restrict__ gate, const float* __restrict__ pbt,
    u16* __restrict__ at) {
  __shared__ float pb_s[2048];
  __shared__ float comb[2][32][64];   // partial-O exchange (sh1 -> sh0)
  __shared__ float comb_l[64];
  const int tid = threadIdx.x, lane = tid & 63, wid = tid >> 6;
  const int l31 = lane & 31, l5 = lane >> 5;
  const int rg = wid >> 1, sh = wid & 1;
  const int bid = blockIdx.x;
  const int x = (bid & 7) + ((bid >> 7) << 3);   // XCD swizzle (16 tblks inner)
  const int tblk = (bid >> 3) & 15;              // 64-row tiles
  const int h = x & 15, b = x >> 4;
  const int T0w = tblk * 64 + rg * 32;           // wave's first q-row
  const int T = T0w + l31;                       // this thread's q-row

  #pragma unroll
  for (int i = 0; i < 2; ++i) {
    int idx = (tid + i * 256) * 4;
    *(fv4*)(pb_s + idx) = *(const fv4*)(pbt + (size_t)h * 2048 + idx);
  }

  // Q as B-frag: lane holds Q[t=T][k = c*16 + l5*8 + j]
  short8 qf[4];
  #pragma unroll
  for (int c = 0; c < 4; ++c)
    qf[c] = *(const short8*)(qb + ((size_t)x * 1024 + T) * 64 + c * 16 + l5 * 8);
  const float g = gate[(size_t)x * 1024 + T];

  const u16* kbx = kb + (size_t)x * SPAD * 64;
  const u16* vtx = vt + (size_t)x * 64 * SPAD;

  f32x16 O0 = {}, O1 = {};
  float lsum = 0.f;
  __syncthreads();   // pb_s ready
  const float gFn = g * pb_s[1300];   // bucket-15 value (rel <= -128)
  const float gFp = g * pb_s[800];    // bucket-31 value (rel >= +128)

  #pragma unroll 1
  for (int i = 0; i < 8; ++i) {
    const int ic = sh * 8 + i;
    const int s0 = ic * 64;
    // K as A-frag: rows s = s0 + ss*32 + l31, k-chunks of 16 over d
    short8 ka[2][4];
    #pragma unroll
    for (int ss = 0; ss < 2; ++ss)
      #pragma unroll
      for (int c = 0; c < 4; ++c)
        ka[ss][c] = *(const short8*)(kbx + (size_t)(s0 + ss * 32 + l31) * 64 + c * 16 + l5 * 8);
    // V^T as A-frag: rows d = ds*32 + l31, k-chunks of 16 over s
    short8 va[2][4];
    #pragma unroll
    for (int ds = 0; ds < 2; ++ds)
      #pragma unroll
      for (int c = 0; c < 4; ++c)
        va[ds][c] = *(const short8*)(vtx + (size_t)(ds * 32 + l31) * SPAD + s0 + c * 16 + l5 * 8);
    // QK^T
    f32x16 sc0 = {}, sc1 = {};
    __builtin_amdgcn_s_setprio(1);
    #pragma unroll
    for (int c = 0; c < 4; ++c) {
      sc0 = __builtin_amdgcn_mfma_f32_32x32x16_bf16(ka[0][c], qf[c], sc0, 0, 0, 0);
      sc1 = __builtin_amdgcn_mfma_f32_32x32x16_bf16(ka[1][c], qf[c], sc1, 0, 0, 0);
    }
    __builtin_amdgcn_s_setprio(0);
    // bias + exp2 (fixed max) + scalar-l + truncate-pack to bf16 pairs
    const int base = 1024 + T - s0;
    u32 pk[16];
    const bool farN = (s0 <= T0w - 191);   // whole wave: rel <= -128 -> bucket 15
    const bool farP = (s0 >= T0w + 159);   // whole wave: rel >= +128 -> bucket 31
    if (farN | farP) {
      const float gf = farN ? gFn : gFp;
      #pragma unroll
      for (int r = 0; r < 16; r += 2) {
        float p0 = exp2f(sc0[r] + gf), p1 = exp2f(sc0[r + 1] + gf);
        lsum += p0 + p1;
        pk[r >> 1] = (__builtin_bit_cast(u32, p1) & 0xFFFF0000u) |
                     (__builtin_bit_cast(u32, p0) >> 16);
      }
      #pragma unroll
      for (int r = 0; r < 16; r += 2) {
        float p0 = exp2f(sc1[r] + gf), p1 = exp2f(sc1[r + 1] + gf);
        lsum += p0 + p1;
        pk[8 + (r >> 1)] = (__builtin_bit_cast(u32, p1) & 0xFFFF0000u) |
                           (__builtin_bit_cast(u32, p0) >> 16);
      }
    } else {
      #pragma unroll
      for (int r = 0; r < 16; r += 2) {
        int soff = (r & 3) + 8 * (r >> 2) + 4 * l5;
        float p0 = exp2f(sc0[r]     + g * pb_s[base - soff]);
        float p1 = exp2f(sc0[r + 1] + g * pb_s[base - soff - 1]);
        lsum += p0 + p1;
        pk[r >> 1] = (__builtin_bit_cast(u32, p1) & 0xFFFF0000u) |
                     (__builtin_bit_cast(u32, p0) >> 16);
      }
      #pragma unroll
      for (int r = 0; r < 16; r += 2) {
        int soff = 32 + (r & 3) + 8 * (r >> 2) + 4 * l5;
        float p0 = exp2f(sc1[r]     + g * pb_s[base - soff]);
        float p1 = exp2f(sc1[r + 1] + g * pb_s[base - soff - 1]);
        lsum += p0 + p1;
        pk[8 + (r >> 1)] = (__builtin_bit_cast(u32, p1) & 0xFFFF0000u) |
                           (__builtin_bit_cast(u32, p0) >> 16);
      }
    }
    // P repack via permlane32_swap + PV
    __builtin_amdgcn_s_setprio(1);
    #pragma unroll
    for (int ss = 0; ss < 2; ++ss) {
      u32 a0 = pk[ss * 8 + 0], a1 = pk[ss * 8 + 1];
      u32 b0 = pk[ss * 8 + 2], b1 = pk[ss * 8 + 3];
      asm volatile("v_permlane32_swap_b32 %0, %1" : "+v"(a0), "+v"(b0));
      asm volatile("v_permlane32_swap_b32 %0, %1" : "+v"(a1), "+v"(b1));
      u32x4 f0v = { a0, a1, b0, b1 };
      short8 pf0 = __builtin_bit_cast(short8, f0v);
      O0 = __builtin_amdgcn_mfma_f32_32x32x16_bf16(va[0][ss * 2], pf0, O0, 0, 0, 0);
      O1 = __builtin_amdgcn_mfma_f32_32x32x16_bf16(va[1][ss * 2], pf0, O1, 0, 0, 0);
      u32 c0 = pk[ss * 8 + 4], c1 = pk[ss * 8 + 5];
      u32 d0 = pk[ss * 8 + 6], d1 = pk[ss * 8 + 7];
      asm volatile("v_permlane32_swap_b32 %0, %1" : "+v"(c0), "+v"(d0));
      asm volatile("v_permlane32_swap_b32 %0, %1" : "+v"(c1), "+v"(d1));
      u32x4 f1v = { c0, c1, d0, d1 };
      short8 pf1 = __builtin_bit_cast(short8, f1v);
      O0 = __builtin_amdgcn_mfma_f32_32x32x16_bf16(va[0][ss * 2 + 1], pf1, O0, 0, 0, 0);
      O1 = __builtin_amdgcn_mfma_f32_32x32x16_bf16(va[1][ss * 2 + 1], pf1, O1, 0, 0, 0);
    }
    __builtin_amdgcn_s_setprio(0);
  }

  lsum += __shfl_xor(lsum, 32);

  if (sh) {
    // ---- tail: s = 1024 (sh1 only), folded into partial O and lsum ----
    float dot = 0.f;
    #pragma unroll
    for (int c = 0; c < 4; ++c) {
      short8 kt = *(const short8*)(kbx + (size_t)1024 * 64 + c * 16 + l5 * 8);
      #pragma unroll
      for (int j = 0; j < 8; ++j)
        dot += bf2f((u16)qf[c][j]) * bf2f((u16)kt[j]);
    }
    dot += __shfl_xor(dot, 32);
    float p_t = exp2f(dot + g * pb_s[T]);
    lsum += p_t;
    #pragma unroll
    for (int ds = 0; ds < 2; ++ds)
      #pragma unroll
      for (int q2 = 0; q2 < 4; ++q2) {
        int d0 = ds * 32 + q2 * 8 + l5 * 4;
        #pragma unroll
        for (int e = 0; e < 4; ++e) {
          float vtl = bf2f(vtx[(size_t)(d0 + e) * SPAD + 1024]);
          if (ds) O1[q2 * 4 + e] += p_t * vtl; else O0[q2 * 4 + e] += p_t * vtl;
        }
      }
    // write partials to LDS (XOR-swizzled d)
    #pragma unroll
    for (int ds = 0; ds < 2; ++ds)
      #pragma unroll
      for (int q2 = 0; q2 < 4; ++q2) {
        int d0 = ds * 32 + q2 * 8 + l5 * 4;
        int dsw = d0 ^ ((l31 & 15) << 2);
        f32x4 v;
        #pragma unroll
        for (int e = 0; e < 4; ++e) v[e] = ds ? O1[q2 * 4 + e] : O0[q2 * 4 + e];
        *(f32x4*)(&comb[rg][l31][dsw]) = v;
      }
    if (l5 == 0) comb_l[rg * 32 + l31] = lsum;
  }
  __syncthreads();
  if (!sh) {
    const float linv = 1.0f / (lsum + comb_l[rg * 32 + l31]);
    #pragma unroll
    for (int ds = 0; ds < 2; ++ds) {
      #pragma unroll
      for (int q2 = 0; q2 < 4; ++q2) {
        int d0 = ds * 32 + q2 * 8 + l5 * 4;
        int dsw = d0 ^ ((l31 & 15) << 2);
        f32x4 pv = *(const f32x4*)(&comb[rg][l31][dsw]);
        u16x4 ov;
        #pragma unroll
        for (int e = 0; e < 4; ++e) {
          float o = ((ds ? O1[q2 * 4 + e] : O0[q2 * 4 + e]) + pv[e]) * linv;
          ov[e] = f2bf(o);
        }
        *(u16x4*)(at + ((size_t)(T * 4 + b)) * 1024 + h * 64 + d0) = ov;
      }
    }
  }
}

// ---------------- output projection GEMM ------------------------------------
__global__ __launch_bounds__(256, 2) void k_out_gemm(const u16* __restrict__ at, const u16* __restrict__ wt3,
                                                     const float* __restrict__ obias, float* __restrict__ out) {
  __shared__ u16 lds[8192];
  f32x4 acc[4][4];
  #pragma unroll
  for (int i = 0; i < 4; ++i)
    #pragma unroll
    for (int j = 0; j < 4; ++j) acc[i][j] = (f32x4){0.f, 0.f, 0.f, 0.f};
  const int m0 = blockIdx.y * 128, n0 = blockIdx.x * 128;
  gemm_tile(at, wt3, m0, n0, lds, lds + 4096, acc);
  const int lane = threadIdx.x & 63, wid = threadIdx.x >> 6;
  const int wm = wid >> 1, wn = wid & 1, l15 = lane & 15, l4 = lane >> 4;
  #pragma unroll
  for (int ni = 0; ni < 4; ++ni) {
    int col = n0 + wn * 64 + ni * 16 + l15;
    float bv = obias[col];
    #pragma unroll
    for (int mi = 0; mi < 4; ++mi) {
      #pragma unroll
      for (int r = 0; r < 4; ++r) {
        int row = m0 + wm * 64 + mi * 16 + l4 * 4 + r;
        out[(size_t)row * 1024 + col] = acc[mi][ni][r] + bv;
      }
    }
  }
}

extern "C" void kernel_launch(void* const* d_in, const int* in_sizes, int n_in,
                              void* d_out, int out_size, void* d_ws, size_t ws_size,
                              hipStream_t stream) {
  const float* query   = (const float*)d_in[0];
  const float* q_w     = (const float*)d_in[1];
  const float* q_b     = (const float*)d_in[2];
  const float* k_w     = (const float*)d_in[3];
  const float* k_b     = (const float*)d_in[4];
  const float* v_w     = (const float*)d_in[5];
  const float* v_b     = (const float*)d_in[6];
  const float* out_w   = (const float*)d_in[7];
  const float* out_b   = (const float*)d_in[8];
  const float* rel_emb = (const float*)d_in[9];
  const float* grep_w  = (const float*)d_in[10];
  const float* grep_b  = (const float*)d_in[11];
  const float* grep_a  = (const float*)d_in[12];
  const float* bias_k  = (const float*)d_in[13];
  const float* bias_v  = (const float*)d_in[14];
  char* ws = (char*)d_ws;
  u16*   qx  = (u16*)(ws + OFF_QX);
  u16*   vt  = (u16*)(ws + OFF_VT);
  u16*   wt  = (u16*)(ws + OFF_WT);
  u16*   qb  = (u16*)(ws + OFF_QB);
  u16*   kb  = (u16*)(ws + OFF_KB);
  u16*   vb  = (u16*)(ws + OFF_VB);
  u16*   at  = (u16*)(ws + OFF_AT);
  float* gate = (float*)(ws + OFF_GATE);
  float* pbt  = (float*)(ws + OFF_PB);
  float* aux  = (float*)(ws + OFF_AUX);
  float* out  = (float*)d_out;

  k_prep<<<dim3(8200), dim3(256), 0, stream>>>(query, qx, q_w, k_w, v_w, out_w, wt,
                                               rel_emb, pbt, grep_w, grep_b, aux);
  k_qkv_gemm<<<dim3(24, 32), dim3(256), 0, stream>>>(qx, wt, q_b, k_b, v_b, qb, kb, vb);
  k_mid<<<dim3(3136), dim3(256), 0, stream>>>(vb, vt, kb, bias_k, bias_v, qb, aux, grep_a, gate);
  k_attn<<<dim3(1024), dim3(256), 0, stream>>>(qb, kb, vt, gate, pbt, at);
  k_out_gemm<<<dim3(8, 32), dim3(256), 0, stream>>>(at, wt + (size_t)3 * EMB * EMB, out_b, out);
}

// Round 8
// 239.310 us; speedup vs baseline: 1.1429x; 1.1429x over previous
//
#include <hip/hip_runtime.h>
#include <stdint.h>

typedef unsigned short u16;
typedef unsigned int   u32;
typedef __attribute__((ext_vector_type(4)))  float f32x4;
typedef __attribute__((ext_vector_type(16))) float f32x16;
typedef __attribute__((ext_vector_type(8)))  short short8;
typedef __attribute__((ext_vector_type(8)))  u16   u16x8;
typedef __attribute__((ext_vector_type(4)))  u16   u16x4;
typedef __attribute__((ext_vector_type(4)))  u32   u32x4;
typedef __attribute__((ext_vector_type(4)))  float fv4;

#define T_LEN 1024
#define EMB   1024
#define SPAD  1088   // padded src len (17*64), valid 0..1024
#define LOG2E 1.44269504f

// workspace layout (bytes) — packed with lifetime sharing
#define OFF_QX   (0ull)
#define OFF_VT   (0ull)          // vt shares qx region (qx dead after qkv)
#define OFF_WT   (8912896ull)
#define OFF_QB   (17301504ull)
#define OFF_KB   (25690112ull)
#define OFF_VB   (34603008ull)
#define OFF_AT   (34603008ull)   // at shares vb region (vb dead after k_mid)
#define OFF_GATE (43515904ull)
#define OFF_PB   (43778048ull)
#define OFF_AUX  (43909120ull)

__device__ __forceinline__ u16 f2bf(float f) {
  uint32_t u = __builtin_bit_cast(uint32_t, f);
  u += 0x7FFFu + ((u >> 16) & 1u);
  return (u16)(u >> 16);
}
__device__ __forceinline__ float bf2f(u16 s) {
  uint32_t u = ((uint32_t)s) << 16;
  return __builtin_bit_cast(float, u);
}
__device__ __forceinline__ void gld_lds16(const void* gp, void* lp) {
  __builtin_amdgcn_global_load_lds(
      (const __attribute__((address_space(1))) uint32_t*)(uintptr_t)(gp),
      (__attribute__((address_space(3))) uint32_t*)(uintptr_t)(lp),
      16, 0, 0);
}

// ================= k_prep: convert_q + transw + pb/aux (blockIdx-ranged) ====
__global__ void k_prep(const float* __restrict__ q, u16* __restrict__ qx,
                       const float* __restrict__ w0, const float* __restrict__ w1,
                       const float* __restrict__ w2, const float* __restrict__ w3,
                       u16* __restrict__ wt,
                       const float* __restrict__ rel_emb, float* __restrict__ pbtab,
                       const float* __restrict__ grep_w, const float* __restrict__ grep_b,
                       float* __restrict__ aux) {
  __shared__ float tile[32][33];
  const int bid = blockIdx.x, tid = threadIdx.x;
  if (bid < 4096) {
    // query f32 -> bf16
    int i = bid * 256 + tid;
    fv4 v = *((const fv4*)q + i);
    u16x4 o = { f2bf(v[0]), f2bf(v[1]), f2bf(v[2]), f2bf(v[3]) };
    *((u16x4*)qx + i) = o;
  } else if (bid < 8192) {
    // weight transpose + convert: wt[z][n][k] = w_z[k][n]
    int b2 = bid - 4096;
    int z = b2 >> 10, xy = b2 & 1023;
    int r0 = (xy >> 5) * 32, c0 = (xy & 31) * 32;
    const float* w = (z == 0) ? w0 : (z == 1) ? w1 : (z == 2) ? w2 : w3;
    int tx = tid & 31, ty = tid >> 5;
    #pragma unroll
    for (int j = 0; j < 32; j += 8)
      tile[ty + j][tx] = w[(size_t)(r0 + ty + j) * EMB + c0 + tx];
    __syncthreads();
    u16* o = wt + (size_t)z * EMB * EMB;
    #pragma unroll
    for (int j = 0; j < 32; j += 8)
      o[(size_t)(c0 + ty + j) * EMB + r0 + tx] = f2bf(tile[tx][ty + j]);
  } else {
    // REVERSED pb table (pre-scaled by log2e): pbtab[h][i] = pb(rel=1024-i)*log2e
    int i = (bid - 8192) * 256 + tid;    // 0..2047
    int rel = 1024 - i;
    int bucket = (rel > 0) ? 16 : 0;
    int r = rel < 0 ? -rel : rel;
    int bidx;
    if (r < 8) bidx = r;
    else {
      float lf = __logf((float)r / 8.0f + 1e-6f) * (1.0f / logf(16.0f)) * 8.0f;
      int large = 8 + (int)lf;
      bidx = large < 15 ? large : 15;
    }
    bucket += bidx;
    #pragma unroll
    for (int hh = 0; hh < 16; ++hh) pbtab[hh * 2048 + i] = rel_emb[bucket * 16 + hh] * LOG2E;
    if (bid == 8192) {
      if (tid < 64) {
        float s = 0.f;
        #pragma unroll
        for (int j = 0; j < 8; ++j) s += grep_w[tid * 8 + j];
        aux[tid] = s;
      } else if (tid == 64) {
        float s = 0.f;
        #pragma unroll
        for (int j = 0; j < 8; ++j) s += grep_b[j];
        aux[64] = s;
      }
    }
  }
}

// ---------------- m97-style 128x128 bf16 GEMM core (B^T input) --------------
__device__ __forceinline__ void gemm_tile(const u16* __restrict__ A, const u16* __restrict__ Bt,
                                          int m0, int n0, u16* As, u16* Bs, f32x4 acc[4][4]) {
  const int tid = threadIdx.x;
  const int lane = tid & 63, wid = tid >> 6;
  const int wm = wid >> 1, wn = wid & 1;
  const int l15 = lane & 15, l4 = lane >> 4;
  for (int kt = 0; kt < EMB; kt += 32) {
    #pragma unroll
    for (int i = 0; i < 2; ++i) {
      int cw = wid * 64 + i * 256;   // wave-uniform chunk base
      int c = cw + lane;
      int row = c >> 2, cb = c & 3;
      gld_lds16(A  + (size_t)(m0 + row) * EMB + kt + cb * 8, (char*)As + (size_t)cw * 16);
      gld_lds16(Bt + (size_t)(n0 + row) * EMB + kt + cb * 8, (char*)Bs + (size_t)cw * 16);
    }
    __syncthreads();
    short8 a[4], b[4];
    #pragma unroll
    for (int f = 0; f < 4; ++f) {
      a[f] = *(const short8*)(As + (wm * 64 + f * 16 + l15) * 32 + l4 * 8);
      b[f] = *(const short8*)(Bs + (wn * 64 + f * 16 + l15) * 32 + l4 * 8);
    }
    #pragma unroll
    for (int mi = 0; mi < 4; ++mi)
      #pragma unroll
      for (int ni = 0; ni < 4; ++ni)
        acc[mi][ni] = __builtin_amdgcn_mfma_f32_16x16x32_bf16(a[mi], b[ni], acc[mi][ni], 0, 0, 0);
    __syncthreads();
  }
}

// ---------------- fused QKV projection GEMM (N = 3072), scrambled scatter ---
__global__ __launch_bounds__(256, 2) void k_qkv_gemm(const u16* __restrict__ qx, const u16* __restrict__ wt,
    const float* __restrict__ qbias, const float* __restrict__ kbias, const float* __restrict__ vbias,
    u16* __restrict__ qb, u16* __restrict__ kb, u16* __restrict__ vb) {
  __shared__ u16 lds[8192];
  f32x4 acc[4][4];
  #pragma unroll
  for (int i = 0; i < 4; ++i)
    #pragma unroll
    for (int j = 0; j < 4; ++j) acc[i][j] = (f32x4){0.f, 0.f, 0.f, 0.f};
  const int m0 = blockIdx.y * 128, n0g = blockIdx.x * 128;   // n0g in [0,3072)
  gemm_tile(qx, wt, m0, n0g, lds, lds + 4096, acc);          // wt is [3072][1024]
  const int z = n0g >> 10;
  const float* bias = (z == 0) ? qbias : (z == 1) ? kbias : vbias;
  const int lane = threadIdx.x & 63, wid = threadIdx.x >> 6;
  const int wm = wid >> 1, wn = wid & 1, l15 = lane & 15, l4 = lane >> 4;
  #pragma unroll
  for (int ni = 0; ni < 4; ++ni) {
    int colg = n0g + wn * 64 + ni * 16 + l15;
    int col = colg & 1023;
    float bv = bias[col];
    int h = col >> 6, d = col & 63;
    #pragma unroll
    for (int mi = 0; mi < 4; ++mi) {
      #pragma unroll
      for (int r = 0; r < 4; ++r) {
        int row = m0 + wm * 64 + mi * 16 + l4 * 4 + r;
        int t = row >> 2, b = row & 3;     // input rows are (t,b) interleaved
        float v = acc[mi][ni][r] + bv;
        if (z == 0) {
          int x = b * 16 + (t >> 6), u = ((t & 63) << 4) + h;
          qb[((size_t)x * 1024 + u) * 64 + d] = f2bf(v * (LOG2E / 256.0f));
        } else {
          int w = t * 16 + h;
          int j = w / 1025;
          int u = w - j * 1025;
          int x = b * 16 + j;
          if (z == 1) kb[((size_t)x * SPAD + u) * 64 + d] = f2bf(v);
          else        vb[((size_t)x * SPAD + u) * 64 + d] = f2bf(v);
        }
      }
    }
  }
}

// ================= k_mid: vtrans + bias_kv injection + gate =================
__global__ void k_mid(const u16* __restrict__ vb, u16* __restrict__ vt, u16* __restrict__ kb,
                      const float* __restrict__ bias_k, const float* __restrict__ bias_v,
                      const u16* __restrict__ qb, const float* __restrict__ aux,
                      const float* __restrict__ grep_a, float* __restrict__ gate) {
  __shared__ u16 t[64][72];
  const int bid = blockIdx.x, tid = threadIdx.x;
  if (bid < 1088) {
    // V transpose vb[x][u][d] -> vt[x][d][u], with bias_v row injection
    const int x = bid / 17, uc = bid - (bid / 17) * 17;
    const int u0 = uc * 64;
    const int ur = tid >> 2, c0 = (tid & 3) * 16;
    const u16* src = vb + ((size_t)x * SPAD + u0 + ur) * 64 + c0;
    u16x8 a0 = *(const u16x8*)(src);
    u16x8 a1 = *(const u16x8*)(src + 8);
    const int ug = u0 + ur;
    if ((x & 15) == 15 && ug >= 1009 && ug <= 1024) {
      const float* bs = bias_v + (ug - 1009) * 64 + c0;   // bias_v[h][d], h = ug-1009
      #pragma unroll
      for (int i = 0; i < 8; ++i) { a0[i] = f2bf(bs[i]); a1[i] = f2bf(bs[8 + i]); }
    }
    *(u16x8*)(&t[ur][c0]) = a0;
    *(u16x8*)(&t[ur][c0 + 8]) = a1;
    __syncthreads();
    const int d = tid >> 2, j = tid & 3;
    u16x8 o0, o1;
    #pragma unroll
    for (int i = 0; i < 8; ++i) o0[i] = t[j * 16 + i][d];
    #pragma unroll
    for (int i = 0; i < 8; ++i) o1[i] = t[j * 16 + 8 + i][d];
    u16* dst = vt + ((size_t)x * 64 + d) * SPAD + u0 + j * 16;
    *(u16x8*)(dst) = o0;
    *(u16x8*)(dst + 8) = o1;
    // bias_k rows (x%16==15, u=1009..1024) written by the uc==16 blocks
    if ((x & 15) == 15 && uc == 16) {
      int k = tid * 4;                 // 0..1023, 16 rows x 64 d
      int hh = k >> 6, dd = k & 63;
      u16x4 kv;
      #pragma unroll
      for (int e = 0; e < 4; ++e) kv[e] = f2bf(bias_k[hh * 64 + dd + e]);
      *(u16x4*)(kb + ((size_t)x * SPAD + 1009 + hh) * 64 + dd) = kv;
    }
  } else {
    // gate[x][u] = sigmoid(q_row . wsum + bg) * grep_a[x&15]
    int gb = bid - 1088;
    int lane = tid & 63, wid = tid >> 6;
    int row0 = (gb * 4 + wid) * 8;
    int sub = lane >> 3, d0 = (lane & 7) * 8;
    int item = row0 + sub;
    u16x8 q8 = *(const u16x8*)(qb + (size_t)item * 64 + d0);
    float acc = 0.f;
    #pragma unroll
    for (int j = 0; j < 8; ++j) acc += bf2f(q8[j]) * aux[d0 + j];
    acc += __shfl_xor(acc, 1);
    acc += __shfl_xor(acc, 2);
    acc += __shfl_xor(acc, 4);
    if ((lane & 7) == 0) {
      float v = acc * (256.0f / LOG2E) + aux[64];
      float s = 1.0f / (1.0f + __expf(-v));
      gate[item] = s * grep_a[(item >> 10) & 15];
    }
  }
}

// ---------------- fused flash attention v7 ----------------------------------
// v6's s-split (2 row-groups x 2 s-halves, grid 1024) WITHOUT the VGPR cap
// that caused v7's scratch spill. Softmax->repack->PV done per 32-s half to
// keep transient pressure low (target <=128 VGPR for 4 waves/SIMD).
__global__ __launch_bounds__(256, 2) void k_attn(const u16* __restrict__ qb, const u16* __restrict__ kb,
    const u16* __restrict__ vt, const float* __restrict__ gate, const float* __restrict__ pbt,
    u16* __restrict__ at) {
  __shared__ float pb_s[2048];
  __shared__ float comb[2][32][64];   // partial-O exchange (sh1 -> sh0)
  __shared__ float comb_l[64];
  const int tid = threadIdx.x, lane = tid & 63, wid = tid >> 6;
  const int l31 = lane & 31, l5 = lane >> 5;
  const int rg = wid >> 1, sh = wid & 1;
  const int bid = blockIdx.x;
  const int x = (bid & 7) + ((bid >> 7) << 3);   // XCD swizzle (16 tblks inner)
  const int tblk = (bid >> 3) & 15;              // 64-row tiles
  const int h = x & 15, b = x >> 4;
  const int T0w = tblk * 64 + rg * 32;           // wave's first q-row
  const int T = T0w + l31;                       // this thread's q-row

  #pragma unroll
  for (int i = 0; i < 2; ++i) {
    int idx = (tid + i * 256) * 4;
    *(fv4*)(pb_s + idx) = *(const fv4*)(pbt + (size_t)h * 2048 + idx);
  }

  // Q as B-frag: lane holds Q[t=T][k = c*16 + l5*8 + j]
  short8 qf[4];
  #pragma unroll
  for (int c = 0; c < 4; ++c)
    qf[c] = *(const short8*)(qb + ((size_t)x * 1024 + T) * 64 + c * 16 + l5 * 8);
  const float g = gate[(size_t)x * 1024 + T];

  const u16* kbx = kb + (size_t)x * SPAD * 64;
  const u16* vtx = vt + (size_t)x * 64 * SPAD;

  f32x16 O0 = {}, O1 = {};
  float lsum = 0.f;
  __syncthreads();   // pb_s ready
  const float gFn = g * pb_s[1300];   // bucket-15 value (rel <= -128)
  const float gFp = g * pb_s[800];    // bucket-31 value (rel >= +128)

  #pragma unroll 1
  for (int i = 0; i < 8; ++i) {
    const int ic = sh * 8 + i;
    const int s0 = ic * 64;
    // K as A-frag: rows s = s0 + ss*32 + l31, k-chunks of 16 over d
    short8 ka[2][4];
    #pragma unroll
    for (int ss = 0; ss < 2; ++ss)
      #pragma unroll
      for (int c = 0; c < 4; ++c)
        ka[ss][c] = *(const short8*)(kbx + (size_t)(s0 + ss * 32 + l31) * 64 + c * 16 + l5 * 8);
    // V^T as A-frag: rows d = ds*32 + l31, k-chunks of 16 over s
    short8 va[2][4];
    #pragma unroll
    for (int ds = 0; ds < 2; ++ds)
      #pragma unroll
      for (int c = 0; c < 4; ++c)
        va[ds][c] = *(const short8*)(vtx + (size_t)(ds * 32 + l31) * SPAD + s0 + c * 16 + l5 * 8);
    // QK^T (both halves: sc0 = s in [s0,s0+32), sc1 = [s0+32,s0+64))
    f32x16 sc0 = {}, sc1 = {};
    __builtin_amdgcn_s_setprio(1);
    #pragma unroll
    for (int c = 0; c < 4; ++c) {
      sc0 = __builtin_amdgcn_mfma_f32_32x32x16_bf16(ka[0][c], qf[c], sc0, 0, 0, 0);
      sc1 = __builtin_amdgcn_mfma_f32_32x32x16_bf16(ka[1][c], qf[c], sc1, 0, 0, 0);
    }
    __builtin_amdgcn_s_setprio(0);
    const int base = 1024 + T - s0;
    const bool farN = (s0 <= T0w - 191);   // whole wave: rel <= -128 -> bucket 15
    const bool farP = (s0 >= T0w + 159);   // whole wave: rel >= +128 -> bucket 31
    const bool far = farN | farP;
    const float gf = farN ? gFn : gFp;
    // ---- half ss=0: softmax + repack + PV (pk liveness limited to 8) ----
    #pragma unroll
    for (int ss = 0; ss < 2; ++ss) {
      const f32x16& sc = ss ? sc1 : sc0;
      u32 pk[8];
      if (far) {
        #pragma unroll
        for (int r = 0; r < 16; r += 2) {
          float p0 = exp2f(sc[r] + gf), p1 = exp2f(sc[r + 1] + gf);
          lsum += p0 + p1;
          pk[r >> 1] = (__builtin_bit_cast(u32, p1) & 0xFFFF0000u) |
                       (__builtin_bit_cast(u32, p0) >> 16);
        }
      } else {
        #pragma unroll
        for (int r = 0; r < 16; r += 2) {
          int soff = ss * 32 + (r & 3) + 8 * (r >> 2) + 4 * l5;
          float p0 = exp2f(sc[r]     + g * pb_s[base - soff]);
          float p1 = exp2f(sc[r + 1] + g * pb_s[base - soff - 1]);
          lsum += p0 + p1;
          pk[r >> 1] = (__builtin_bit_cast(u32, p1) & 0xFFFF0000u) |
                       (__builtin_bit_cast(u32, p0) >> 16);
        }
      }
      __builtin_amdgcn_s_setprio(1);
      u32 a0 = pk[0], a1 = pk[1], b0 = pk[2], b1 = pk[3];
      asm volatile("v_permlane32_swap_b32 %0, %1" : "+v"(a0), "+v"(b0));
      asm volatile("v_permlane32_swap_b32 %0, %1" : "+v"(a1), "+v"(b1));
      u32x4 f0v = { a0, a1, b0, b1 };
      short8 pf0 = __builtin_bit_cast(short8, f0v);
      O0 = __builtin_amdgcn_mfma_f32_32x32x16_bf16(va[0][ss * 2], pf0, O0, 0, 0, 0);
      O1 = __builtin_amdgcn_mfma_f32_32x32x16_bf16(va[1][ss * 2], pf0, O1, 0, 0, 0);
      u32 c0 = pk[4], c1 = pk[5], d0 = pk[6], d1 = pk[7];
      asm volatile("v_permlane32_swap_b32 %0, %1" : "+v"(c0), "+v"(d0));
      asm volatile("v_permlane32_swap_b32 %0, %1" : "+v"(c1), "+v"(d1));
      u32x4 f1v = { c0, c1, d0, d1 };
      short8 pf1 = __builtin_bit_cast(short8, f1v);
      O0 = __builtin_amdgcn_mfma_f32_32x32x16_bf16(va[0][ss * 2 + 1], pf1, O0, 0, 0, 0);
      O1 = __builtin_amdgcn_mfma_f32_32x32x16_bf16(va[1][ss * 2 + 1], pf1, O1, 0, 0, 0);
      __builtin_amdgcn_s_setprio(0);
    }
  }

  lsum += __shfl_xor(lsum, 32);

  if (sh) {
    // ---- tail: s = 1024 (sh1 only), folded into partial O and lsum ----
    float dot = 0.f;
    #pragma unroll
    for (int c = 0; c < 4; ++c) {
      short8 kt = *(const short8*)(kbx + (size_t)1024 * 64 + c * 16 + l5 * 8);
      #pragma unroll
      for (int j = 0; j < 8; ++j)
        dot += bf2f((u16)qf[c][j]) * bf2f((u16)kt[j]);
    }
    dot += __shfl_xor(dot, 32);
    float p_t = exp2f(dot + g * pb_s[T]);
    lsum += p_t;
    #pragma unroll
    for (int ds = 0; ds < 2; ++ds)
      #pragma unroll
      for (int q2 = 0; q2 < 4; ++q2) {
        int d0 = ds * 32 + q2 * 8 + l5 * 4;
        #pragma unroll
        for (int e = 0; e < 4; ++e) {
          float vtl = bf2f(vtx[(size_t)(d0 + e) * SPAD + 1024]);
          if (ds) O1[q2 * 4 + e] += p_t * vtl; else O0[q2 * 4 + e] += p_t * vtl;
        }
      }
    // write partials to LDS (XOR-swizzled d)
    #pragma unroll
    for (int ds = 0; ds < 2; ++ds)
      #pragma unroll
      for (int q2 = 0; q2 < 4; ++q2) {
        int d0 = ds * 32 + q2 * 8 + l5 * 4;
        int dsw = d0 ^ ((l31 & 15) << 2);
        f32x4 v;
        #pragma unroll
        for (int e = 0; e < 4; ++e) v[e] = ds ? O1[q2 * 4 + e] : O0[q2 * 4 + e];
        *(f32x4*)(&comb[rg][l31][dsw]) = v;
      }
    if (l5 == 0) comb_l[rg * 32 + l31] = lsum;
  }
  __syncthreads();
  if (!sh) {
    const float linv = 1.0f / (lsum + comb_l[rg * 32 + l31]);
    #pragma unroll
    for (int ds = 0; ds < 2; ++ds) {
      #pragma unroll
      for (int q2 = 0; q2 < 4; ++q2) {
        int d0 = ds * 32 + q2 * 8 + l5 * 4;
        int dsw = d0 ^ ((l31 & 15) << 2);
        f32x4 pv = *(const f32x4*)(&comb[rg][l31][dsw]);
        u16x4 ov;
        #pragma unroll
        for (int e = 0; e < 4; ++e) {
          float o = ((ds ? O1[q2 * 4 + e] : O0[q2 * 4 + e]) + pv[e]) * linv;
          ov[e] = f2bf(o);
        }
        *(u16x4*)(at + ((size_t)(T * 4 + b)) * 1024 + h * 64 + d0) = ov;
      }
    }
  }
}

// ---------------- output projection GEMM ------------------------------------
__global__ __launch_bounds__(256, 2) void k_out_gemm(const u16* __restrict__ at, const u16* __restrict__ wt3,
                                                     const float* __restrict__ obias, float* __restrict__ out) {
  __shared__ u16 lds[8192];
  f32x4 acc[4][4];
  #pragma unroll
  for (int i = 0; i < 4; ++i)
    #pragma unroll
    for (int j = 0; j < 4; ++j) acc[i][j] = (f32x4){0.f, 0.f, 0.f, 0.f};
  const int m0 = blockIdx.y * 128, n0 = blockIdx.x * 128;
  gemm_tile(at, wt3, m0, n0, lds, lds + 4096, acc);
  const int lane = threadIdx.x & 63, wid = threadIdx.x >> 6;
  const int wm = wid >> 1, wn = wid & 1, l15 = lane & 15, l4 = lane >> 4;
  #pragma unroll
  for (int ni = 0; ni < 4; ++ni) {
    int col = n0 + wn * 64 + ni * 16 + l15;
    float bv = obias[col];
    #pragma unroll
    for (int mi = 0; mi < 4; ++mi) {
      #pragma unroll
      for (int r = 0; r < 4; ++r) {
        int row = m0 + wm * 64 + mi * 16 + l4 * 4 + r;
        out[(size_t)row * 1024 + col] = acc[mi][ni][r] + bv;
      }
    }
  }
}

extern "C" void kernel_launch(void* const* d_in, const int* in_sizes, int n_in,
                              void* d_out, int out_size, void* d_ws, size_t ws_size,
                              hipStream_t stream) {
  const float* query   = (const float*)d_in[0];
  const float* q_w     = (const float*)d_in[1];
  const float* q_b     = (const float*)d_in[2];
  const float* k_w     = (const float*)d_in[3];
  const float* k_b     = (const float*)d_in[4];
  const float* v_w     = (const float*)d_in[5];
  const float* v_b     = (const float*)d_in[6];
  const float* out_w   = (const float*)d_in[7];
  const float* out_b   = (const float*)d_in[8];
  const float* rel_emb = (const float*)d_in[9];
  const float* grep_w  = (const float*)d_in[10];
  const float* grep_b  = (const float*)d_in[11];
  const float* grep_a  = (const float*)d_in[12];
  const float* bias_k  = (const float*)d_in[13];
  const float* bias_v  = (const float*)d_in[14];
  char* ws = (char*)d_ws;
  u16*   qx  = (u16*)(ws + OFF_QX);
  u16*   vt  = (u16*)(ws + OFF_VT);
  u16*   wt  = (u16*)(ws + OFF_WT);
  u16*   qb  = (u16*)(ws + OFF_QB);
  u16*   kb  = (u16*)(ws + OFF_KB);
  u16*   vb  = (u16*)(ws + OFF_VB);
  u16*   at  = (u16*)(ws + OFF_AT);
  float* gate = (float*)(ws + OFF_GATE);
  float* pbt  = (float*)(ws + OFF_PB);
  float* aux  = (float*)(ws + OFF_AUX);
  float* out  = (float*)d_out;

  k_prep<<<dim3(8200), dim3(256), 0, stream>>>(query, qx, q_w, k_w, v_w, out_w, wt,
                                               rel_emb, pbt, grep_w, grep_b, aux);
  k_qkv_gemm<<<dim3(24, 32), dim3(256), 0, stream>>>(qx, wt, q_b, k_b, v_b, qb, kb, vb);
  k_mid<<<dim3(3136), dim3(256), 0, stream>>>(vb, vt, kb, bias_k, bias_v, qb, aux, grep_a, gate);
  k_attn<<<dim3(1024), dim3(256), 0, stream>>>(qb, kb, vt, gate, pbt, at);
  k_out_gemm<<<dim3(8, 32), dim3(256), 0, stream>>>(at, wt + (size_t)3 * EMB * EMB, out_b, out);
}

// Round 10
// 210.630 us; speedup vs baseline: 1.2985x; 1.1362x over previous
//
#include <hip/hip_runtime.h>
#include <stdint.h>

typedef unsigned short u16;
typedef unsigned int   u32;
typedef __attribute__((ext_vector_type(4)))  float f32x4;
typedef __attribute__((ext_vector_type(8)))  short short8;
typedef __attribute__((ext_vector_type(8)))  u16   u16x8;
typedef __attribute__((ext_vector_type(4)))  u16   u16x4;
typedef __attribute__((ext_vector_type(4)))  float fv4;

#define T_LEN 1024
#define EMB   1024
#define SPAD  1088   // padded src len (17*64), valid 0..1024
#define LOG2E 1.44269504f

// workspace layout (bytes) — packed with lifetime sharing
#define OFF_QX   (0ull)
#define OFF_VT   (0ull)          // vt shares qx region (qx dead after qkv)
#define OFF_WT   (8912896ull)
#define OFF_QB   (17301504ull)
#define OFF_KB   (25690112ull)
#define OFF_VB   (34603008ull)
#define OFF_AT   (34603008ull)   // at shares vb region (vb dead after k_mid)
#define OFF_GATE (43515904ull)
#define OFF_PB   (43778048ull)
#define OFF_AUX  (43909120ull)

__device__ __forceinline__ u16 f2bf(float f) {
  uint32_t u = __builtin_bit_cast(uint32_t, f);
  u += 0x7FFFu + ((u >> 16) & 1u);
  return (u16)(u >> 16);
}
__device__ __forceinline__ float bf2f(u16 s) {
  uint32_t u = ((uint32_t)s) << 16;
  return __builtin_bit_cast(float, u);
}
__device__ __forceinline__ void gld_lds16(const void* gp, void* lp) {
  __builtin_amdgcn_global_load_lds(
      (const __attribute__((address_space(1))) uint32_t*)(uintptr_t)(gp),
      (__attribute__((address_space(3))) uint32_t*)(uintptr_t)(lp),
      16, 0, 0);
}

// ================= k_prep: convert_q + transw + pb/aux (blockIdx-ranged) ====
__global__ void k_prep(const float* __restrict__ q, u16* __restrict__ qx,
                       const float* __restrict__ w0, const float* __restrict__ w1,
                       const float* __restrict__ w2, const float* __restrict__ w3,
                       u16* __restrict__ wt,
                       const float* __restrict__ rel_emb, float* __restrict__ pbtab,
                       const float* __restrict__ grep_w, const float* __restrict__ grep_b,
                       float* __restrict__ aux) {
  __shared__ float tile[32][33];
  const int bid = blockIdx.x, tid = threadIdx.x;
  if (bid < 4096) {
    // query f32 -> bf16
    int i = bid * 256 + tid;
    fv4 v = *((const fv4*)q + i);
    u16x4 o = { f2bf(v[0]), f2bf(v[1]), f2bf(v[2]), f2bf(v[3]) };
    *((u16x4*)qx + i) = o;
  } else if (bid < 8192) {
    // weight transpose + convert: wt[z][n][k] = w_z[k][n]
    int b2 = bid - 4096;
    int z = b2 >> 10, xy = b2 & 1023;
    int r0 = (xy >> 5) * 32, c0 = (xy & 31) * 32;
    const float* w = (z == 0) ? w0 : (z == 1) ? w1 : (z == 2) ? w2 : w3;
    int tx = tid & 31, ty = tid >> 5;
    #pragma unroll
    for (int j = 0; j < 32; j += 8)
      tile[ty + j][tx] = w[(size_t)(r0 + ty + j) * EMB + c0 + tx];
    __syncthreads();
    u16* o = wt + (size_t)z * EMB * EMB;
    #pragma unroll
    for (int j = 0; j < 32; j += 8)
      o[(size_t)(c0 + ty + j) * EMB + r0 + tx] = f2bf(tile[tx][ty + j]);
  } else {
    // REVERSED pb table (pre-scaled by log2e): pbtab[h][i] = pb(rel=1024-i)*log2e
    int i = (bid - 8192) * 256 + tid;    // 0..2047
    int rel = 1024 - i;
    int bucket = (rel > 0) ? 16 : 0;
    int r = rel < 0 ? -rel : rel;
    int bidx;
    if (r < 8) bidx = r;
    else {
      float lf = __logf((float)r / 8.0f + 1e-6f) * (1.0f / logf(16.0f)) * 8.0f;
      int large = 8 + (int)lf;
      bidx = large < 15 ? large : 15;
    }
    bucket += bidx;
    #pragma unroll
    for (int hh = 0; hh < 16; ++hh) pbtab[hh * 2048 + i] = rel_emb[bucket * 16 + hh] * LOG2E;
    if (bid == 8192) {
      if (tid < 64) {
        float s = 0.f;
        #pragma unroll
        for (int j = 0; j < 8; ++j) s += grep_w[tid * 8 + j];
        aux[tid] = s;
      } else if (tid == 64) {
        float s = 0.f;
        #pragma unroll
        for (int j = 0; j < 8; ++j) s += grep_b[j];
        aux[64] = s;
      }
    }
  }
}

// ---------------- m97-style 128x128 bf16 GEMM core (B^T input) --------------
__device__ __forceinline__ void gemm_tile(const u16* __restrict__ A, const u16* __restrict__ Bt,
                                          int m0, int n0, u16* As, u16* Bs, f32x4 acc[4][4]) {
  const int tid = threadIdx.x;
  const int lane = tid & 63, wid = tid >> 6;
  const int wm = wid >> 1, wn = wid & 1;
  const int l15 = lane & 15, l4 = lane >> 4;
  for (int kt = 0; kt < EMB; kt += 32) {
    #pragma unroll
    for (int i = 0; i < 2; ++i) {
      int cw = wid * 64 + i * 256;   // wave-uniform chunk base
      int c = cw + lane;
      int row = c >> 2, cb = c & 3;
      gld_lds16(A  + (size_t)(m0 + row) * EMB + kt + cb * 8, (char*)As + (size_t)cw * 16);
      gld_lds16(Bt + (size_t)(n0 + row) * EMB + kt + cb * 8, (char*)Bs + (size_t)cw * 16);
    }
    __syncthreads();
    short8 a[4], b[4];
    #pragma unroll
    for (int f = 0; f < 4; ++f) {
      a[f] = *(const short8*)(As + (wm * 64 + f * 16 + l15) * 32 + l4 * 8);
      b[f] = *(const short8*)(Bs + (wn * 64 + f * 16 + l15) * 32 + l4 * 8);
    }
    #pragma unroll
    for (int mi = 0; mi < 4; ++mi)
      #pragma unroll
      for (int ni = 0; ni < 4; ++ni)
        acc[mi][ni] = __builtin_amdgcn_mfma_f32_16x16x32_bf16(a[mi], b[ni], acc[mi][ni], 0, 0, 0);
    __syncthreads();
  }
}

// ---------------- fused QKV projection GEMM (N = 3072), scrambled scatter ---
__global__ __launch_bounds__(256, 2) void k_qkv_gemm(const u16* __restrict__ qx, const u16* __restrict__ wt,
    const float* __restrict__ qbias, const float* __restrict__ kbias, const float* __restrict__ vbias,
    u16* __restrict__ qb, u16* __restrict__ kb, u16* __restrict__ vb) {
  __shared__ u16 lds[8192];
  f32x4 acc[4][4];
  #pragma unroll
  for (int i = 0; i < 4; ++i)
    #pragma unroll
    for (int j = 0; j < 4; ++j) acc[i][j] = (f32x4){0.f, 0.f, 0.f, 0.f};
  const int m0 = blockIdx.y * 128, n0g = blockIdx.x * 128;   // n0g in [0,3072)
  gemm_tile(qx, wt, m0, n0g, lds, lds + 4096, acc);          // wt is [3072][1024]
  const int z = n0g >> 10;
  const float* bias = (z == 0) ? qbias : (z == 1) ? kbias : vbias;
  const int lane = threadIdx.x & 63, wid = threadIdx.x >> 6;
  const int wm = wid >> 1, wn = wid & 1, l15 = lane & 15, l4 = lane >> 4;
  #pragma unroll
  for (int ni = 0; ni < 4; ++ni) {
    int colg = n0g + wn * 64 + ni * 16 + l15;
    int col = colg & 1023;
    float bv = bias[col];
    int h = col >> 6, d = col & 63;
    #pragma unroll
    for (int mi = 0; mi < 4; ++mi) {
      #pragma unroll
      for (int r = 0; r < 4; ++r) {
        int row = m0 + wm * 64 + mi * 16 + l4 * 4 + r;
        int t = row >> 2, b = row & 3;     // input rows are (t,b) interleaved
        float v = acc[mi][ni][r] + bv;
        if (z == 0) {
          int x = b * 16 + (t >> 6), u = ((t & 63) << 4) + h;
          qb[((size_t)x * 1024 + u) * 64 + d] = f2bf(v * (LOG2E / 256.0f));
        } else {
          int w = t * 16 + h;
          int j = w / 1025;
          int u = w - j * 1025;
          int x = b * 16 + j;
          if (z == 1) kb[((size_t)x * SPAD + u) * 64 + d] = f2bf(v);
          else        vb[((size_t)x * SPAD + u) * 64 + d] = f2bf(v);
        }
      }
    }
  }
}

// ================= k_mid: vtrans + bias_kv injection + gate =================
__global__ void k_mid(const u16* __restrict__ vb, u16* __restrict__ vt, u16* __restrict__ kb,
                      const float* __restrict__ bias_k, const float* __restrict__ bias_v,
                      const u16* __restrict__ qb, const float* __restrict__ aux,
                      const float* __restrict__ grep_a, float* __restrict__ gate) {
  __shared__ u16 t[64][72];
  const int bid = blockIdx.x, tid = threadIdx.x;
  if (bid < 1088) {
    // V transpose vb[x][u][d] -> vt[x][d][u], with bias_v row injection
    const int x = bid / 17, uc = bid - (bid / 17) * 17;
    const int u0 = uc * 64;
    const int ur = tid >> 2, c0 = (tid & 3) * 16;
    const u16* src = vb + ((size_t)x * SPAD + u0 + ur) * 64 + c0;
    u16x8 a0 = *(const u16x8*)(src);
    u16x8 a1 = *(const u16x8*)(src + 8);
    const int ug = u0 + ur;
    if ((x & 15) == 15 && ug >= 1009 && ug <= 1024) {
      const float* bs = bias_v + (ug - 1009) * 64 + c0;   // bias_v[h][d], h = ug-1009
      #pragma unroll
      for (int i = 0; i < 8; ++i) { a0[i] = f2bf(bs[i]); a1[i] = f2bf(bs[8 + i]); }
    }
    *(u16x8*)(&t[ur][c0]) = a0;
    *(u16x8*)(&t[ur][c0 + 8]) = a1;
    __syncthreads();
    const int d = tid >> 2, j = tid & 3;
    u16x8 o0, o1;
    #pragma unroll
    for (int i = 0; i < 8; ++i) o0[i] = t[j * 16 + i][d];
    #pragma unroll
    for (int i = 0; i < 8; ++i) o1[i] = t[j * 16 + 8 + i][d];
    u16* dst = vt + ((size_t)x * 64 + d) * SPAD + u0 + j * 16;
    *(u16x8*)(dst) = o0;
    *(u16x8*)(dst + 8) = o1;
    // bias_k rows (x%16==15, u=1009..1024) written by the uc==16 blocks
    if ((x & 15) == 15 && uc == 16) {
      int k = tid * 4;                 // 0..1023, 16 rows x 64 d
      int hh = k >> 6, dd = k & 63;
      u16x4 kv;
      #pragma unroll
      for (int e = 0; e < 4; ++e) kv[e] = f2bf(bias_k[hh * 64 + dd + e]);
      *(u16x4*)(kb + ((size_t)x * SPAD + 1009 + hh) * 64 + dd) = kv;
    }
  } else {
    // gate[x][u] = sigmoid(q_row . wsum + bg) * grep_a[x&15]
    int gb = bid - 1088;
    int lane = tid & 63, wid = tid >> 6;
    int row0 = (gb * 4 + wid) * 8;
    int sub = lane >> 3, d0 = (lane & 7) * 8;
    int item = row0 + sub;
    u16x8 q8 = *(const u16x8*)(qb + (size_t)item * 64 + d0);
    float acc = 0.f;
    #pragma unroll
    for (int j = 0; j < 8; ++j) acc += bf2f(q8[j]) * aux[d0 + j];
    acc += __shfl_xor(acc, 1);
    acc += __shfl_xor(acc, 2);
    acc += __shfl_xor(acc, 4);
    if ((lane & 7) == 0) {
      float v = acc * (256.0f / LOG2E) + aux[64];
      float s = 1.0f / (1.0f + __expf(-v));
      gate[item] = s * grep_a[(item >> 10) & 15];
    }
  }
}

// ---------------- fused flash attention (round-4 proven LDS-staged v3 + far-bucket pb)
// 256 thr / 4 waves, 32 q-rows per wave, KVBLK=64, double-buffered swizzled LDS,
// fixed-max base-2 softmax. Far chunks (|rel|>=128) use uniform bucket bias.
__global__ __launch_bounds__(256, 2) void k_attn(const u16* __restrict__ qb, const u16* __restrict__ kb,
    const u16* __restrict__ vt, const float* __restrict__ gate, const float* __restrict__ pbt,
    u16* __restrict__ at) {
  __shared__ float pb_s[2048];
  __shared__ u16 Ksh[2 * 4096];   // [buf][64 k][64 d] swizzled
  __shared__ u16 Vsh[2 * 4096];   // [buf][64 d][64 k] swizzled (V^T)
  __shared__ u16 Psh[4 * 2048];   // per-wave [32 q][64 k] swizzled
  const int tid = threadIdx.x, lane = tid & 63, wid = tid >> 6;
  const int l15 = lane & 15, l4 = lane >> 4;
  const int bid = blockIdx.x;
  const int x = (bid & 7) + ((bid >> 6) << 3);   // XCD swizzle
  const int tblk = (bid >> 3) & 7;
  const int h = x & 15, b = x >> 4;
  const int qrow0 = tblk * 128 + wid * 32;

  #pragma unroll
  for (int i = 0; i < 2; ++i) {
    int idx = (tid + i * 256) * 4;
    *(fv4*)(pb_s + idx) = *(const fv4*)(pbt + (size_t)h * 2048 + idx);
  }

  // Q fragments + gate in registers
  short8 qa[2][2];
  #pragma unroll
  for (int pf = 0; pf < 2; ++pf)
    #pragma unroll
    for (int ks = 0; ks < 2; ++ks)
      qa[pf][ks] = *(const short8*)(qb + ((size_t)x * 1024 + qrow0 + pf * 16 + l15) * 64 + ks * 32 + l4 * 8);
  float g[2][4];
  #pragma unroll
  for (int pf = 0; pf < 2; ++pf)
    #pragma unroll
    for (int r = 0; r < 4; ++r)
      g[pf][r] = gate[(size_t)x * 1024 + qrow0 + pf * 16 + l4 * 4 + r];

  // staging source pointers (pre-swizzled global addresses, linear LDS dest)
  const u16* kbx = kb + (size_t)x * SPAD * 64;
  const u16* vtx = vt + (size_t)x * 64 * SPAD;
  const int ra = tid >> 3, sa = tid & 7;          // rows 0..31
  const int rb = ra + 32;                          // rows 32..63
  const u16* sK0 = kbx + ra * 64 + ((sa * 8) ^ ((ra & 7) << 3));
  const u16* sK1 = kbx + rb * 64 + ((sa * 8) ^ ((rb & 7) << 3));
  const u16* sV0 = vtx + (size_t)ra * SPAD + ((sa * 8) ^ ((ra & 7) << 3));
  const u16* sV1 = vtx + (size_t)rb * SPAD + ((sa * 8) ^ ((rb & 7) << 3));

  // fragment read offsets (swizzled)
  const int swz = (l15 & 7) << 3;
  int kfO[4][2];
  #pragma unroll
  for (int f = 0; f < 4; ++f)
    #pragma unroll
    for (int ks = 0; ks < 2; ++ks)
      kfO[f][ks] = (f * 16 + l15) * 64 + ((ks * 32 + l4 * 8) ^ swz);
  int paO[2][2];
  #pragma unroll
  for (int pf = 0; pf < 2; ++pf)
    #pragma unroll
    for (int ks = 0; ks < 2; ++ks)
      paO[pf][ks] = (pf * 16 + l15) * 64 + ((ks * 32 + l4 * 8) ^ swz);
  u16* Pw = Psh + wid * 2048;

  f32x4 O[2][4];
  float l_[2][4];
  #pragma unroll
  for (int pf = 0; pf < 2; ++pf) {
    #pragma unroll
    for (int df = 0; df < 4; ++df) O[pf][df] = (f32x4){0.f, 0.f, 0.f, 0.f};
    #pragma unroll
    for (int r = 0; r < 4; ++r) l_[pf][r] = 0.f;
  }

  // prologue: stage chunk 0 into buf 0
  gld_lds16(sK0, (char*)Ksh + wid * 1024);
  gld_lds16(sK1, (char*)Ksh + 4096 + wid * 1024);
  gld_lds16(sV0, (char*)Vsh + wid * 1024);
  gld_lds16(sV1, (char*)Vsh + 4096 + wid * 1024);
  sK0 += 4096; sK1 += 4096; sV0 += 64; sV1 += 64;
  __asm__ volatile("s_waitcnt vmcnt(0)" ::: "memory");
  __syncthreads();

  int cur = 0;
  for (int ic = 0; ic < 16; ++ic) {
    const int nxt = cur ^ 1;
    char* Kn = (char*)(Ksh + nxt * 4096);
    char* Vn = (char*)(Vsh + nxt * 4096);
    if (ic < 15) {
      gld_lds16(sK0, Kn + wid * 1024);
      gld_lds16(sK1, Kn + 4096 + wid * 1024);
      gld_lds16(sV0, Vn + wid * 1024);
      gld_lds16(sV1, Vn + 4096 + wid * 1024);
      sK0 += 4096; sK1 += 4096; sV0 += 64; sV1 += 64;
    } else if (wid < 2) {
      // stage K tail rows 1024..1039 linearly (only row 0 is real; rest garbage-safe)
      int ro = (wid * 64 + lane) >> 3, so = lane & 7;
      gld_lds16(kbx + (size_t)(1024 + ro) * 64 + so * 8, Kn + wid * 1024);
    }
    const u16* Kc = Ksh + cur * 4096;
    const u16* Vc = Vsh + cur * 4096;

    // QK^T
    f32x4 sc[2][4];
    #pragma unroll
    for (int pf = 0; pf < 2; ++pf)
      #pragma unroll
      for (int nf = 0; nf < 4; ++nf) sc[pf][nf] = (f32x4){0.f, 0.f, 0.f, 0.f};
    #pragma unroll
    for (int nf = 0; nf < 4; ++nf)
      #pragma unroll
      for (int ks = 0; ks < 2; ++ks) {
        short8 kf = *(const short8*)(Kc + kfO[nf][ks]);
        sc[0][nf] = __builtin_amdgcn_mfma_f32_16x16x32_bf16(qa[0][ks], kf, sc[0][nf], 0, 0, 0);
        sc[1][nf] = __builtin_amdgcn_mfma_f32_16x16x32_bf16(qa[1][ks], kf, sc[1][nf], 0, 0, 0);
      }

    // bias + exp2 (fixed max) + partial-l + P store (truncated bf16)
    const int s0 = ic * 64;
    const bool farN = (s0 <= qrow0 - 191);   // whole wave: rel <= -128 -> bucket 15
    const bool farP = (s0 >= qrow0 + 159);   // whole wave: rel >= +128 -> bucket 31
    if (farN | farP) {
      const float pbF = farN ? pb_s[1300] : pb_s[800];
      #pragma unroll
      for (int pf = 0; pf < 2; ++pf)
        #pragma unroll
        for (int nf = 0; nf < 4; ++nf) {
          #pragma unroll
          for (int r = 0; r < 4; ++r) {
            float sv = sc[pf][nf][r] + g[pf][r] * pbF;
            float p = exp2f(sv);
            l_[pf][r] += p;
            const int prow = pf * 16 + l4 * 4 + r;
            Pw[prow * 64 + ((nf * 16 + l15) ^ ((prow & 7) << 3))] =
                (u16)(__builtin_bit_cast(uint32_t, p) >> 16);
          }
        }
    } else {
      #pragma unroll
      for (int pf = 0; pf < 2; ++pf)
        #pragma unroll
        for (int nf = 0; nf < 4; ++nf) {
          const int base = 1024 + qrow0 + pf * 16 + l4 * 4 - (s0 + nf * 16 + l15);
          #pragma unroll
          for (int r = 0; r < 4; ++r) {
            float sv = sc[pf][nf][r] + g[pf][r] * pb_s[base + r];
            float p = exp2f(sv);
            l_[pf][r] += p;
            const int prow = pf * 16 + l4 * 4 + r;
            Pw[prow * 64 + ((nf * 16 + l15) ^ ((prow & 7) << 3))] =
                (u16)(__builtin_bit_cast(uint32_t, p) >> 16);
          }
        }
    }
    __asm__ volatile("s_waitcnt lgkmcnt(0)" ::: "memory");
    __builtin_amdgcn_sched_barrier(0);

    // PV
    #pragma unroll
    for (int ks = 0; ks < 2; ++ks) {
      short8 pa0 = *(const short8*)(Pw + paO[0][ks]);
      short8 pa1 = *(const short8*)(Pw + paO[1][ks]);
      #pragma unroll
      for (int df = 0; df < 4; ++df) {
        short8 vbf = *(const short8*)(Vc + kfO[df][ks]);
        O[0][df] = __builtin_amdgcn_mfma_f32_16x16x32_bf16(pa0, vbf, O[0][df], 0, 0, 0);
        O[1][df] = __builtin_amdgcn_mfma_f32_16x16x32_bf16(pa1, vbf, O[1][df], 0, 0, 0);
      }
    }
    __asm__ volatile("s_waitcnt vmcnt(0)" ::: "memory");
    __syncthreads();
    cur = nxt;
  }

  // ---- tail: s = 1024 ----
  const u16* Kt = Ksh + cur * 4096;
  short8 kt0 = *(const short8*)(Kt + l15 * 64 + l4 * 8);
  short8 kt1 = *(const short8*)(Kt + l15 * 64 + 32 + l4 * 8);
  f32x4 sc0[2];
  #pragma unroll
  for (int pf = 0; pf < 2; ++pf) {
    sc0[pf] = (f32x4){0.f, 0.f, 0.f, 0.f};
    sc0[pf] = __builtin_amdgcn_mfma_f32_16x16x32_bf16(qa[pf][0], kt0, sc0[pf], 0, 0, 0);
    sc0[pf] = __builtin_amdgcn_mfma_f32_16x16x32_bf16(qa[pf][1], kt1, sc0[pf], 0, 0, 0);
  }
  float vtail[4];
  #pragma unroll
  for (int df = 0; df < 4; ++df)
    vtail[df] = bf2f(vt[((size_t)x * 64 + df * 16 + l15) * SPAD + 1024]);

  float pt[2][4], linv[2][4];
  #pragma unroll
  for (int pf = 0; pf < 2; ++pf)
    #pragma unroll
    for (int r = 0; r < 4; ++r) {
      float dotv = __shfl(sc0[pf][r], lane & 48);      // col 0 (s=1024)
      int t = qrow0 + pf * 16 + l4 * 4 + r;
      float se = dotv + g[pf][r] * pb_s[t];            // idx = 1024 + t - 1024
      float p = exp2f(se);
      float ls = l_[pf][r];
      ls += __shfl_xor(ls, 1);
      ls += __shfl_xor(ls, 2);
      ls += __shfl_xor(ls, 4);
      ls += __shfl_xor(ls, 8);
      pt[pf][r] = p;
      linv[pf][r] = 1.0f / (ls + p);
    }

  #pragma unroll
  for (int pf = 0; pf < 2; ++pf)
    #pragma unroll
    for (int df = 0; df < 4; ++df)
      #pragma unroll
      for (int r = 0; r < 4; ++r) {
        int t = qrow0 + pf * 16 + l4 * 4 + r;
        float o = (O[pf][df][r] + pt[pf][r] * vtail[df]) * linv[pf][r];
        at[((size_t)(t * 4 + b)) * 1024 + h * 64 + df * 16 + l15] = f2bf(o);
      }
}

// ---------------- output projection GEMM ------------------------------------
__global__ __launch_bounds__(256, 2) void k_out_gemm(const u16* __restrict__ at, const u16* __restrict__ wt3,
                                                     const float* __restrict__ obias, float* __restrict__ out) {
  __shared__ u16 lds[8192];
  f32x4 acc[4][4];
  #pragma unroll
  for (int i = 0; i < 4; ++i)
    #pragma unroll
    for (int j = 0; j < 4; ++j) acc[i][j] = (f32x4){0.f, 0.f, 0.f, 0.f};
  const int m0 = blockIdx.y * 128, n0 = blockIdx.x * 128;
  gemm_tile(at, wt3, m0, n0, lds, lds + 4096, acc);
  const int lane = threadIdx.x & 63, wid = threadIdx.x >> 6;
  const int wm = wid >> 1, wn = wid & 1, l15 = lane & 15, l4 = lane >> 4;
  #pragma unroll
  for (int ni = 0; ni < 4; ++ni) {
    int col = n0 + wn * 64 + ni * 16 + l15;
    float bv = obias[col];
    #pragma unroll
    for (int mi = 0; mi < 4; ++mi) {
      #pragma unroll
      for (int r = 0; r < 4; ++r) {
        int row = m0 + wm * 64 + mi * 16 + l4 * 4 + r;
        out[(size_t)row * 1024 + col] = acc[mi][ni][r] + bv;
      }
    }
  }
}

extern "C" void kernel_launch(void* const* d_in, const int* in_sizes, int n_in,
                              void* d_out, int out_size, void* d_ws, size_t ws_size,
                              hipStream_t stream) {
  const float* query   = (const float*)d_in[0];
  const float* q_w     = (const float*)d_in[1];
  const float* q_b     = (const float*)d_in[2];
  const float* k_w     = (const float*)d_in[3];
  const float* k_b     = (const float*)d_in[4];
  const float* v_w     = (const float*)d_in[5];
  const float* v_b     = (const float*)d_in[6];
  const float* out_w   = (const float*)d_in[7];
  const float* out_b   = (const float*)d_in[8];
  const float* rel_emb = (const float*)d_in[9];
  const float* grep_w  = (const float*)d_in[10];
  const float* grep_b  = (const float*)d_in[11];
  const float* grep_a  = (const float*)d_in[12];
  const float* bias_k  = (const float*)d_in[13];
  const float* bias_v  = (const float*)d_in[14];
  char* ws = (char*)d_ws;
  u16*   qx  = (u16*)(ws + OFF_QX);
  u16*   vt  = (u16*)(ws + OFF_VT);
  u16*   wt  = (u16*)(ws + OFF_WT);
  u16*   qb  = (u16*)(ws + OFF_QB);
  u16*   kb  = (u16*)(ws + OFF_KB);
  u16*   vb  = (u16*)(ws + OFF_VB);
  u16*   at  = (u16*)(ws + OFF_AT);
  float* gate = (float*)(ws + OFF_GATE);
  float* pbt  = (float*)(ws + OFF_PB);
  float* aux  = (float*)(ws + OFF_AUX);
  float* out  = (float*)d_out;

  k_prep<<<dim3(8200), dim3(256), 0, stream>>>(query, qx, q_w, k_w, v_w, out_w, wt,
                                               rel_emb, pbt, grep_w, grep_b, aux);
  k_qkv_gemm<<<dim3(24, 32), dim3(256), 0, stream>>>(qx, wt, q_b, k_b, v_b, qb, kb, vb);
  k_mid<<<dim3(3136), dim3(256), 0, stream>>>(vb, vt, kb, bias_k, bias_v, qb, aux, grep_a, gate);
  k_attn<<<dim3(512), dim3(256), 0, stream>>>(qb, kb, vt, gate, pbt, at);
  k_out_gemm<<<dim3(8, 32), dim3(256), 0, stream>>>(at, wt + (size_t)3 * EMB * EMB, out_b, out);
}